// Round 3
// baseline (375.860 us; speedup 1.0000x reference)
//
#include <hip/hip_runtime.h>

// SeparableConv3D fused: x[8,3,32,256,256] fp32, depthwise K=5 cross-corr
// along W, H, T, zero 'same' padding.
//
// v4: WAVE-AUTONOMOUS, ZERO BARRIERS. Each 64-lane wave owns a 4-row x
// 64-col output strip for all t. It stages its own 8-row x 68-col x-halo
// slice into a PRIVATE double-buffered LDS region (intra-wave LDS
// ordering is guaranteed by lgkmcnt waits the compiler inserts — no
// __syncthreads anywhere). W-conv is recomputed per H-conv task (5x
// redundancy, ~120 FMA/lane/iter) which eliminates the shared sy tile
// and with it all cross-wave coupling. 24 independent waves/CU hide HBM
// latency by TLP; 2-deep register prefetch (pA/pB) hides it by ILP too.
//
// Traffic: ~217 MB read + 201 MB write -> ~66 us floor @ 6.3 TB/s.
// Intra-block halo overlap (32 staged rows vs 20 unique) is L1-absorbed.
//
// LDS: 4 waves x 2 bufs x 640 floats = 20480 B -> 6 blocks/CU (grid-limited).
// Bank check (16-lane phases): reads (r0+k)*68 + 4*s -> 2 lanes per 4-bank
// span = free; float2 writes contiguous -> each bank once per phase.

#define N_  8
#define C_  3
#define T_  32
#define H_  256
#define W_  256
#define K_  5
#define HW_ (H_ * W_)

#define TH 16          // block output rows (4 waves x 4)
#define TW 64          // block output cols
#define XSTR 68        // floats per staged x row (64 + 2*2 halo)
#define XF2  272       // float2 per slice region (8 rows * 34)
#define XPADF 640      // padded floats per region (320 float2) - dump slots

typedef float nfloat4 __attribute__((ext_vector_type(4)));

__global__ __launch_bounds__(256)
void sep3d_wave(const float* __restrict__ x,
                const float* __restrict__ w1,
                const float* __restrict__ w2,
                const float* __restrict__ w3,
                float* __restrict__ out)
{
    // [wave][buf][floats]; private per wave -> no cross-wave hazards.
    __shared__ float sxAll[4][2][XPADF];    // 20480 B

    const int tid = threadIdx.x;
    const int wv  = tid >> 6;
    const int ln  = tid & 63;
    const int nc  = blockIdx.z;             // n*C + c
    const int c   = nc % C_;
    const int h0  = blockIdx.y * TH + wv * 4;   // wave's first output row
    const int w0  = blockIdx.x * TW;

    const float* xnc = x   + (size_t)nc * (T_ * HW_);
    float*       onc = out + (size_t)nc * (T_ * HW_);

    float k1[K_], k2[K_], k3[K_];
#pragma unroll
    for (int k = 0; k < K_; ++k) {
        k1[k] = w1[c * K_ + k];
        k2[k] = w2[c * K_ + k];
        k3[k] = w3[c * K_ + k];
    }

    // ---- Staging descriptors (t-invariant): 272 float2 tasks / 64 lanes ----
    int  goff[5];      // clamped global float offset within slice
    bool gok[5];
    int  loff[5];      // LDS float offset within region
#pragma unroll
    for (int j = 0; j < 5; ++j) {
        int i   = ln + 64 * j;              // [0, 320)
        int row = i / 34;
        int c2  = i - row * 34;
        int gh  = h0 - 2 + row;
        int gw  = w0 - 2 + 2 * c2;          // even -> float2 8B-aligned
        gok[j]  = (i < XF2) && ((unsigned)gh < H_) && (gw >= 0) && (gw + 1 < W_);
        goff[j] = gok[j] ? (gh * W_ + gw) : 0;
        loff[j] = 2 * i;                    // row*68 + 2*c2 (+ dump pad)
    }

    // ---- Compute-task constants: 1 output float4 per lane ----
    const int r0 = ln >> 4;                 // 0..3 : output row within strip
    const int s3 = ln & 15;                 // 0..15: 4-col segment
    float* gst = onc + (size_t)(h0 + r0) * W_ + (w0 + 4 * s3);

    // T-conv register ring: at start of iter t,
    // a0=partial out(t-2), a1=out(t-1), a2=out(t), a3=out(t+1).
    nfloat4 a0 = {0,0,0,0}, a1 = a0, a2 = a0, a3 = a0;

    float2 pA[5], pB[5];

    // Always-load-then-select: branchless, freely schedulable loads.
#define LOADP(P, tt) do {                                                   \
    const int tc_ = ((tt) < T_) ? (tt) : 0;                                 \
    const bool tok_ = (tt) < T_;                                            \
    const float* xt_ = xnc + (size_t)tc_ * HW_;                             \
    _Pragma("unroll") for (int j = 0; j < 5; ++j) {                         \
        float2 v_ = *(const float2*)(xt_ + goff[j]);                        \
        bool ok_ = tok_ && gok[j];                                          \
        (P)[j].x = ok_ ? v_.x : 0.0f;                                       \
        (P)[j].y = ok_ ? v_.y : 0.0f;                                       \
    } } while (0)

#define WRITEP(P, B) do {                                                   \
    float* sw_ = &sxAll[wv][(B)][0];                                        \
    _Pragma("unroll") for (int j = 0; j < 5; ++j)                           \
        *(float2*)(sw_ + loff[j]) = (P)[j];                                 \
    } while (0)

    // Fused W+H conv from private LDS buf B (slice tt), T-ring update+store.
#define COMPUTE(B, tt) do {                                                 \
    const float* sr_ = &sxAll[wv][(B)][0];                                  \
    nfloat4 z = {0,0,0,0};                                                  \
    _Pragma("unroll") for (int k = 0; k < K_; ++k) {                        \
        const float4* pp = (const float4*)(sr_ + (r0 + k) * XSTR + 4 * s3); \
        float4 aa = pp[0], bb = pp[1];                                      \
        float y0 = aa.x*k1[0]+aa.y*k1[1]+aa.z*k1[2]+aa.w*k1[3]+bb.x*k1[4];  \
        float y1 = aa.y*k1[0]+aa.z*k1[1]+aa.w*k1[2]+bb.x*k1[3]+bb.y*k1[4];  \
        float y2 = aa.z*k1[0]+aa.w*k1[1]+bb.x*k1[2]+bb.y*k1[3]+bb.z*k1[4];  \
        float y3 = aa.w*k1[0]+bb.x*k1[1]+bb.y*k1[2]+bb.z*k1[3]+bb.w*k1[4];  \
        z.x += y0 * k2[k]; z.y += y1 * k2[k];                               \
        z.z += y2 * k2[k]; z.w += y3 * k2[k];                               \
    }                                                                       \
    nfloat4 dn;                                                             \
    dn.x = a0.x + z.x * k3[4]; dn.y = a0.y + z.y * k3[4];                   \
    dn.z = a0.z + z.z * k3[4]; dn.w = a0.w + z.w * k3[4];                   \
    if ((tt) >= 2)                                                          \
        __builtin_nontemporal_store(dn,                                     \
            (nfloat4*)(gst + (size_t)((tt) - 2) * HW_));                    \
    a0.x = a1.x + z.x * k3[3]; a0.y = a1.y + z.y * k3[3];                   \
    a0.z = a1.z + z.z * k3[3]; a0.w = a1.w + z.w * k3[3];                   \
    a1.x = a2.x + z.x * k3[2]; a1.y = a2.y + z.y * k3[2];                   \
    a1.z = a2.z + z.z * k3[2]; a1.w = a2.w + z.w * k3[2];                   \
    a2.x = a3.x + z.x * k3[1]; a2.y = a3.y + z.y * k3[1];                   \
    a2.z = a3.z + z.z * k3[1]; a2.w = a3.w + z.w * k3[1];                   \
    a3.x = z.x * k3[0]; a3.y = z.y * k3[0];                                 \
    a3.z = z.z * k3[0]; a3.w = z.w * k3[0];                                 \
    } while (0)

    // ---- Prologue: slice 0 -> buf0; prefetch slices 1 (pA) and 2 (pB) ----
    LOADP(pA, 0);
    WRITEP(pA, 0);
    LOADP(pA, 1);
    LOADP(pB, 2);

    // ---- Main loop: unrolled by 2, static buffer/prefetch-set indices ----
    for (int t = 0; t < T_; t += 2) {
        COMPUTE(0, t);          // reads buf0 = slice t
        WRITEP(pA, 1);          // slice t+1 -> buf1 (waits vmcnt on pA)
        LOADP(pA, t + 3);       // in flight ~1.5 iterations
        COMPUTE(1, t + 1);      // reads buf1 = slice t+1
        WRITEP(pB, 0);          // slice t+2 -> buf0
        LOADP(pB, t + 4);
    }

    // Epilogue: out(30) = a0, out(31) = a1 (z beyond T is zero padding)
    __builtin_nontemporal_store(a0, (nfloat4*)(gst + (size_t)30 * HW_));
    __builtin_nontemporal_store(a1, (nfloat4*)(gst + (size_t)31 * HW_));

#undef LOADP
#undef WRITEP
#undef COMPUTE
}

extern "C" void kernel_launch(void* const* d_in, const int* in_sizes, int n_in,
                              void* d_out, int out_size, void* d_ws, size_t ws_size,
                              hipStream_t stream)
{
    const float* x  = (const float*)d_in[0];
    const float* w1 = (const float*)d_in[1];
    const float* w2 = (const float*)d_in[2];
    const float* w3 = (const float*)d_in[3];
    float* out = (float*)d_out;

    dim3 grid(W_ / TW, H_ / TH, N_ * C_);   // 4 x 16 x 24 = 1536 blocks
    sep3d_wave<<<grid, 256, 0, stream>>>(x, w1, w2, w3, out);
}